// Round 3
// 2224.024 us; speedup vs baseline: 1.2684x; 1.2684x over previous
//
#include <hip/hip_runtime.h>
#include <hip/hip_bf16.h>
#include <math.h>

#define T_DIM 8192
#define E_DIM 8
#define H_DIM 1024
#define I_DIM 4096

typedef __bf16 bf16x8 __attribute__((ext_vector_type(8)));
typedef float floatx4 __attribute__((ext_vector_type(4)));

__device__ __forceinline__ void async_copy16(const ushort* g, ushort* l) {
  __builtin_amdgcn_global_load_lds(
      (const __attribute__((address_space(1))) unsigned int*)g,
      (__attribute__((address_space(3))) unsigned int*)l, 16, 0, 0);
}

__device__ __forceinline__ bf16x8 ld_frag(const ushort* p) {
  union { uint4 u; bf16x8 b; } c;
  c.u = *(const uint4*)p;
  return c.b;
}

__device__ __forceinline__ ushort f2bs(float f) {
  __hip_bfloat16 h = __float2bfloat16(f);
  return *(ushort*)&h;
}

// ---------------------------------------------------------------------------
// Dtype probe: if x is fp32, even-index ushorts are fp32 mantissa bits ->
// ~31% have bf16-exponent-field >= 0xB0. If x is bf16 ~N(0,1), none do.
// flag = 1 (fp32) / 0 (bf16), written to ws. Deterministic, graph-safe.
// ---------------------------------------------------------------------------
__global__ void probe_dtype_kernel(const ushort* __restrict__ xs, int* flag) {
  __shared__ int cnt;
  if (threadIdx.x == 0) cnt = 0;
  __syncthreads();
  int bad = 0;
  for (int i = threadIdx.x; i < 2048; i += 256) {
    unsigned e = (xs[2 * i] >> 7) & 0xFF;
    if (e >= 0xB0) bad++;
  }
  atomicAdd(&cnt, bad);
  __syncthreads();
  if (threadIdx.x == 0) *flag = (cnt > 64) ? 1 : 0;
}

// ---------------------------------------------------------------------------
// Convert one expert slice x[:, e, :] (row stride = E*H elems, fp32 or bf16
// per *flag) into contiguous bf16 xe[T][H]. One thread per 8 elements.
// Grid: T*H/8/256 = 4096 blocks (exact coverage, all accesses in-bounds).
// ---------------------------------------------------------------------------
__global__ void __launch_bounds__(256)
convert_x_to_bf16(const void* __restrict__ x, size_t off, int src_stride,
                  ushort* __restrict__ xe, const int* __restrict__ flag) {
  const int f32 = *flag;
  const size_t idx = (size_t)blockIdx.x * 256 + threadIdx.x;
  const size_t r = idx >> 7;             // H/8 = 128 chunks per row
  const size_t c = (idx & 127) * 8;
  union { ushort u[8]; uint4 q; } o;
  if (f32) {
    const float* src = (const float*)x + off + r * (size_t)src_stride + c;
    float4 v0 = ((const float4*)src)[0];
    float4 v1 = ((const float4*)src)[1];
    o.u[0] = f2bs(v0.x); o.u[1] = f2bs(v0.y);
    o.u[2] = f2bs(v0.z); o.u[3] = f2bs(v0.w);
    o.u[4] = f2bs(v1.x); o.u[5] = f2bs(v1.y);
    o.u[6] = f2bs(v1.z); o.u[7] = f2bs(v1.w);
  } else {
    const ushort* src = (const ushort*)x + off + r * (size_t)src_stride + c;
    o.q = *(const uint4*)src;
  }
  *(uint4*)&xe[r * H_DIM + c] = o.q;
}

// ---------------------------------------------------------------------------
// Transpose one [rows][cols] slice -> bf16 out[cols][rows]; input fp32 or
// bf16 per *flag. 64x64 tiles, 256 threads.
// ---------------------------------------------------------------------------
__global__ void __launch_bounds__(256)
transpose_to_bf16(const void* __restrict__ in, size_t in_off,
                  ushort* __restrict__ out, int rows, int cols,
                  const int* __restrict__ flag) {
  __shared__ ushort tile[64][65];
  const int f32 = *flag;
  const int c0 = blockIdx.x * 64, r0 = blockIdx.y * 64;
  const int t = threadIdx.x;
  const int lr = t >> 4;            // 0..15
  const int lc = (t & 15) * 4;      // 0..60 step 4
  if (f32) {
    const float* src = (const float*)in + in_off;
#pragma unroll
    for (int j = 0; j < 64; j += 16) {
      float4 v = *(const float4*)&src[(size_t)(r0 + lr + j) * cols + c0 + lc];
      tile[lr + j][lc + 0] = f2bs(v.x);
      tile[lr + j][lc + 1] = f2bs(v.y);
      tile[lr + j][lc + 2] = f2bs(v.z);
      tile[lr + j][lc + 3] = f2bs(v.w);
    }
  } else {
    const ushort* src = (const ushort*)in + in_off;
#pragma unroll
    for (int j = 0; j < 64; j += 16) {
      ushort4 v = *(const ushort4*)&src[(size_t)(r0 + lr + j) * cols + c0 + lc];
      tile[lr + j][lc + 0] = v.x;
      tile[lr + j][lc + 1] = v.y;
      tile[lr + j][lc + 2] = v.z;
      tile[lr + j][lc + 3] = v.w;
    }
  }
  __syncthreads();
#pragma unroll
  for (int j = 0; j < 64; j += 16) {
    ushort4 v;
    v.x = tile[lc + 0][lr + j];
    v.y = tile[lc + 1][lr + j];
    v.z = tile[lc + 2][lr + j];
    v.w = tile[lc + 3][lr + j];
    *(ushort4*)&out[(size_t)(c0 + lr + j) * rows + r0 + lc] = v;
  }
}

// ---------------------------------------------------------------------------
// C[M][N] = A[M][K] * Bt[N][K]^T, fp32 accumulate, 128x128 tile, 4 waves,
// BK=32, mfma_f32_16x16x32_bf16. Bt is always bf16 (pre-transposed in ws).
// A: bf16 (a_mode=0) or per-flag fp32/bf16 (a_mode=1).
// C: bf16 (c_mode=0) or per-flag fp32/bf16 (c_mode=1). Optional exact GELU.
// ---------------------------------------------------------------------------
__global__ void __launch_bounds__(256)
gemm_bt(const void* __restrict__ Avoid, size_t a_off, int lda,
        const ushort* __restrict__ Bt, int ldb,
        void* __restrict__ Cvoid, size_t c_off, int ldc,
        int K, int apply_gelu, int a_mode, int c_mode,
        const int* __restrict__ flag) {
  __shared__ __align__(16) ushort As[128 * 32];  // [row][k]
  __shared__ __align__(16) ushort Bs[128 * 32];  // [n][k]

  const int f32 = *flag;
  const bool a_f32 = a_mode && f32;
  const bool c_f32 = c_mode && f32;

  const int tid = threadIdx.x;
  const int wave = tid >> 6, lane = tid & 63;
  const int quad = lane >> 4, l16 = lane & 15;
  const size_t bm = (size_t)blockIdx.y * 128;
  const size_t bn = (size_t)blockIdx.x * 128;
  const int wm = (wave >> 1) * 64;
  const int wn = (wave & 1) * 64;

  floatx4 acc[4][4] = {};

  // bf16 staging geometry: 512 chunks of 16B; chunk ch -> row=ch>>2, grp=ch&3
  const int ch0 = wave * 64 + lane;
  const int ch1 = ch0 + 256;
  const ushort* Ab = (const ushort*)Avoid + a_off;
  const ushort* ga0 = Ab + (bm + (ch0 >> 2)) * (size_t)lda + (ch0 & 3) * 8;
  const ushort* ga1 = Ab + (bm + (ch1 >> 2)) * (size_t)lda + (ch1 & 3) * 8;
  const ushort* gb0 = Bt + (bn + (ch0 >> 2)) * (size_t)ldb + (ch0 & 3) * 8;
  const ushort* gb1 = Bt + (bn + (ch1 >> 2)) * (size_t)ldb + (ch1 & 3) * 8;
  ushort* la0 = &As[(size_t)(wave * 64) * 8];
  ushort* la1 = &As[(size_t)(wave * 64 + 256) * 8];
  ushort* lb0 = &Bs[(size_t)(wave * 64) * 8];
  ushort* lb1 = &Bs[(size_t)(wave * 64 + 256) * 8];

  // fp32 A staging geometry: thread -> row=tid>>1, khalf=(tid&1)*16
  const float* Af = (const float*)Avoid + a_off;
  const float* gaf = Af + (bm + (tid >> 1)) * (size_t)lda + (size_t)(tid & 1) * 16;
  uint4* lafp = (uint4*)&As[(size_t)(tid >> 1) * 32 + (tid & 1) * 16];

  const ushort* pa = &As[(size_t)(wm + l16) * 32 + quad * 8];
  const ushort* pb = &Bs[(size_t)(wn + l16) * 32 + quad * 8];

  for (int k0 = 0; k0 < K; k0 += 32) {
    if (a_f32) {
      const float* sp = gaf + k0;
      float4 v0 = ((const float4*)sp)[0];
      float4 v1 = ((const float4*)sp)[1];
      float4 v2 = ((const float4*)sp)[2];
      float4 v3 = ((const float4*)sp)[3];
      union { ushort u[16]; uint4 q[2]; } tmp;
      tmp.u[0] = f2bs(v0.x);  tmp.u[1] = f2bs(v0.y);
      tmp.u[2] = f2bs(v0.z);  tmp.u[3] = f2bs(v0.w);
      tmp.u[4] = f2bs(v1.x);  tmp.u[5] = f2bs(v1.y);
      tmp.u[6] = f2bs(v1.z);  tmp.u[7] = f2bs(v1.w);
      tmp.u[8] = f2bs(v2.x);  tmp.u[9] = f2bs(v2.y);
      tmp.u[10] = f2bs(v2.z); tmp.u[11] = f2bs(v2.w);
      tmp.u[12] = f2bs(v3.x); tmp.u[13] = f2bs(v3.y);
      tmp.u[14] = f2bs(v3.z); tmp.u[15] = f2bs(v3.w);
      lafp[0] = tmp.q[0];
      lafp[1] = tmp.q[1];
    } else {
      async_copy16(ga0 + k0, la0);
      async_copy16(ga1 + k0, la1);
    }
    async_copy16(gb0 + k0, lb0);
    async_copy16(gb1 + k0, lb1);
    __syncthreads();

    bf16x8 af[4], bfr[4];
#pragma unroll
    for (int i = 0; i < 4; ++i) af[i] = ld_frag(pa + i * 16 * 32);
#pragma unroll
    for (int i = 0; i < 4; ++i) bfr[i] = ld_frag(pb + i * 16 * 32);
#pragma unroll
    for (int mi = 0; mi < 4; ++mi)
#pragma unroll
      for (int ni = 0; ni < 4; ++ni)
        acc[mi][ni] = __builtin_amdgcn_mfma_f32_16x16x32_bf16(
            af[mi], bfr[ni], acc[mi][ni], 0, 0, 0);
    __syncthreads();
  }

  // C/D layout: col = lane&15, row = (lane>>4)*4 + reg  (m89/m91-verified)
  float* Cf = (float*)Cvoid + c_off;
  __hip_bfloat16* Cb = (__hip_bfloat16*)Cvoid + c_off;
#pragma unroll
  for (int mi = 0; mi < 4; ++mi) {
#pragma unroll
    for (int ni = 0; ni < 4; ++ni) {
      const size_t col = bn + wn + ni * 16 + l16;
      const size_t row0 = bm + wm + mi * 16 + quad * 4;
#pragma unroll
      for (int r = 0; r < 4; ++r) {
        float v = acc[mi][ni][r];
        if (apply_gelu) v = 0.5f * v * (1.0f + erff(v * 0.70710678118654752f));
        if (c_f32) Cf[(row0 + r) * (size_t)ldc + col] = v;
        else       Cb[(row0 + r) * (size_t)ldc + col] = __float2bfloat16(v);
      }
    }
  }
}

extern "C" void kernel_launch(void* const* d_in, const int* in_sizes, int n_in,
                              void* d_out, int out_size, void* d_ws, size_t ws_size,
                              hipStream_t stream) {
  const void* x  = d_in[0];   // [T, E, H]
  const void* wi = d_in[1];   // [E, H, I]
  const void* wo = d_in[2];   // [E, I, H]

  // ws layout (96 MB + 256 B):
  //   [0]          int flag
  //   +256B        wiT_e [I][H] bf16   (8 MB)
  //   +8MB         woT_e [H][I] bf16   (8 MB)
  //   +16MB        h1    [T][I] bf16   (64 MB)
  //   +80MB        xe    [T][H] bf16   (16 MB)   -- only if ws_size allows
  int* flag   = (int*)d_ws;
  ushort* wiT = (ushort*)((char*)d_ws + 256);
  ushort* woT = wiT + (size_t)I_DIM * H_DIM;
  ushort* h1  = woT + (size_t)H_DIM * I_DIM;
  ushort* xe  = h1 + (size_t)T_DIM * I_DIM;

  const size_t need = 256 +
      ((size_t)I_DIM * H_DIM + (size_t)H_DIM * I_DIM +
       (size_t)T_DIM * I_DIM + (size_t)T_DIM * H_DIM) * sizeof(ushort);
  const bool use_xe = (ws_size >= need);

  probe_dtype_kernel<<<1, 256, 0, stream>>>((const ushort*)x, flag);

  for (int e = 0; e < E_DIM; ++e) {
    // wi[e] [H][I] -> wiT [I][H]
    transpose_to_bf16<<<dim3(I_DIM / 64, H_DIM / 64), 256, 0, stream>>>(
        wi, (size_t)e * H_DIM * I_DIM, wiT, H_DIM, I_DIM, flag);
    // wo[e] [I][H] -> woT [H][I]
    transpose_to_bf16<<<dim3(H_DIM / 64, I_DIM / 64), 256, 0, stream>>>(
        wo, (size_t)e * I_DIM * H_DIM, woT, I_DIM, H_DIM, flag);

    if (use_xe) {
      // x[:, e, :] (strided, fp32-or-bf16) -> xe [T][H] bf16 contiguous
      convert_x_to_bf16<<<dim3(T_DIM * H_DIM / 8 / 256), 256, 0, stream>>>(
          x, (size_t)e * H_DIM, E_DIM * H_DIM, xe, flag);

      // GEMM1 + GELU: h1[T,I] = gelu(xe @ wi[e]) — pure async bf16 path
      gemm_bt<<<dim3(I_DIM / 128, T_DIM / 128), 256, 0, stream>>>(
          xe, 0, H_DIM,
          wiT, H_DIM,
          h1, 0, I_DIM,
          H_DIM, /*gelu=*/1, /*a_mode=*/0, /*c_mode=*/0, flag);
    } else {
      // Fallback: read x directly (fp32 staging path, round-0-verified)
      gemm_bt<<<dim3(I_DIM / 128, T_DIM / 128), 256, 0, stream>>>(
          x, (size_t)e * H_DIM, E_DIM * H_DIM,
          wiT, H_DIM,
          h1, 0, I_DIM,
          H_DIM, /*gelu=*/1, /*a_mode=*/1, /*c_mode=*/0, flag);
    }

    // GEMM2: out[:,e,:] = h1 @ wo[e]
    gemm_bt<<<dim3(H_DIM / 128, T_DIM / 128), 256, 0, stream>>>(
        h1, 0, I_DIM,
        woT, I_DIM,
        d_out, (size_t)e * H_DIM, E_DIM * H_DIM,
        I_DIM, /*gelu=*/0, /*a_mode=*/0, /*c_mode=*/1, flag);
  }
}